// Round 9
// baseline (198.159 us; speedup 1.0000x reference)
//
#include <hip/hip_runtime.h>
#include <math.h>
#include <float.h>
#include <limits.h>

// Problem constants
#define PIX    13824   // 64*216
#define QPIX   3456    // 32*108
#define QW     108
#define QH     32
#define NPTS   8192
#define MCAP   3072    // per-quadrant center capacity (expected ~2048, 26 sigma)
#define KT2    27      // QPIX/128 (k4a key tiles)
#define CSPL2  12      // center-splits: each block 2 x 128-center tiles (covers MCAP)

// ---------------------------------------------------------------------------
// K1: feat/value linear maps + fold to [r][k][c] pixel-major + feat inv-norm.
// Blocks 0..215: linmaps (8 waves x 8 outputs). Blocks 216..231: per-chunk
// quadrant counts (was k2a - one fewer dispatch). Also zeroes agg+denom+cnt.
// ---------------------------------------------------------------------------
__device__ __forceinline__ int point_quadrant(float px, float py) {
    // rh = 384/2 = 192 exact, rw = 1296/2 = 648 exact
    return ((py > 192.0f) ? 2 : 0) + ((px > 648.0f) ? 1 : 0);
}

__global__ __launch_bounds__(512) void k1_linmaps(
    const float* __restrict__ x, const float* __restrict__ Wf, const float* __restrict__ bf,
    const float* __restrict__ Wv, const float* __restrict__ bv,
    float* __restrict__ featp, float* __restrict__ valp, float* __restrict__ invn,
    float* __restrict__ aggz,
    const float* __restrict__ points, int* __restrict__ ccnt)
{
    __shared__ float ssq[8][64];
    int t = threadIdx.x;

    // zero agg(786432) + denom(12288) + cnt(12288) = 811008 floats = 202752 float4
    {
        float4 z4 = make_float4(0.f, 0.f, 0.f, 0.f);
        for (int i = blockIdx.x * 512 + t; i < 202752; i += 232 * 512)
            ((float4*)aggz)[i] = z4;
    }

    int lane = t & 63;
    int q = t >> 6;                       // wave id (wave-uniform)

    if (blockIdx.x >= 216) {              // k2a work: wave == 64-point chunk
        int chunk = (blockIdx.x - 216) * 8 + q;
        float2 p = ((const float2*)points)[chunk * 64 + lane];
        int qd = point_quadrant(p.x, p.y);
        #pragma unroll
        for (int r = 0; r < 4; r++) {
            unsigned long long m = __ballot(qd == r);
            if (lane == 0) ccnt[chunk * 4 + r] = __popcll(m);
        }
        return;
    }

    int pix = blockIdx.x * 64 + lane;     // 216*64 = 13824 exact
    int h = pix / 216;
    int w = pix - h * 216;
    int r = ((h >> 5) << 1) | (w >= QW ? 1 : 0);
    int k = (h & 31) * QW + (w >= QW ? w - QW : w);

    float xr[64];
    #pragma unroll
    for (int c = 0; c < 64; c++) xr[c] = x[c * PIX + pix];

    size_t base = ((size_t)(r * QPIX + k)) * 64 + q * 8;
    float ss = 0.0f;
    for (int i = 0; i < 8; i++) {
        int o = q * 8 + i;                // wave-uniform
        float af = bf[o], av = bv[o];
        #pragma unroll
        for (int c = 0; c < 64; c++) {
            af = fmaf(Wf[o * 64 + c], xr[c], af);
            av = fmaf(Wv[o * 64 + c], xr[c], av);
        }
        featp[base + i] = af;
        valp[base + i]  = av;
        ss += af * af;
    }
    ssq[q][lane] = ss;
    __syncthreads();
    if (q == 0) {
        float tot = 0.0f;
        #pragma unroll
        for (int i = 0; i < 8; i++) tot += ssq[i][lane];
        invn[r * QPIX + k] = 1.0f / fmaxf(sqrtf(tot), 1e-12f);
    }
}

// ---------------------------------------------------------------------------
// K2c: per-block redundant scan of chunk counts + ranked order-preserving
// scatter of points into per-quadrant compacted arrays.
// ---------------------------------------------------------------------------
__global__ __launch_bounds__(64) void k2c_scatter(
    const float* __restrict__ points, const int* __restrict__ ccnt,
    float* __restrict__ cp, int* __restrict__ slot, int* __restrict__ counts)
{
    int lane = threadIdx.x;
    int chunk = blockIdx.x;

    // redundant per-block scan: prefix over chunks < my chunk, per quadrant
    int c0[4], c1[4], pre[4];
    #pragma unroll
    for (int r = 0; r < 4; r++) {
        c0[r] = ccnt[lane * 4 + r];
        c1[r] = ccnt[(lane + 64) * 4 + r];
        pre[r] = (lane < chunk ? c0[r] : 0) + (lane + 64 < chunk ? c1[r] : 0);
    }
    #pragma unroll
    for (int d = 1; d < 64; d <<= 1) {
        #pragma unroll
        for (int r = 0; r < 4; r++) pre[r] += __shfl_xor(pre[r], d, 64);
    }
    if (chunk == 0) {   // block 0 also publishes the totals
        int full[4];
        #pragma unroll
        for (int r = 0; r < 4; r++) full[r] = c0[r] + c1[r];
        #pragma unroll
        for (int d = 1; d < 64; d <<= 1) {
            #pragma unroll
            for (int r = 0; r < 4; r++) full[r] += __shfl_xor(full[r], d, 64);
        }
        if (lane == 0) {
            #pragma unroll
            for (int r = 0; r < 4; r++) counts[r] = full[r];
        }
    }

    int n = chunk * 64 + lane;
    float2 p = ((const float2*)points)[n];
    int q = point_quadrant(p.x, p.y);
    unsigned long long below = (lane == 0) ? 0ull : (~0ull >> (64 - lane));
    #pragma unroll
    for (int r = 0; r < 4; r++) {
        unsigned long long m = __ballot(q == r);
        if (q == r) {
            int pos = pre[r] + __popcll(m & below);
            ((float2*)cp)[r * MCAP + pos] = p;
            slot[n] = r * MCAP + pos;
        }
    }
}

// ---------------------------------------------------------------------------
// K3: bilinear gather (border clamp) of feat & value at compacted points;
// slot m == K_r is the phantom (0,0) padded row. 8 channel-groups x 32 points
// per block (256 threads, 8 ch/thread).
// ---------------------------------------------------------------------------
__global__ __launch_bounds__(256) void k3_gather(
    const float* __restrict__ featp, const float* __restrict__ valp,
    const float* __restrict__ cp, const int* __restrict__ counts,
    float* __restrict__ cn, float* __restrict__ vc)
{
    __shared__ float ssq[32][9];
    int r = blockIdx.y;
    int t = threadIdx.x;
    int g = t & 7, p = t >> 3;          // g: channel group (8ch), p: point in tile
    int m = blockIdx.x * 32 + p;
    int K = counts[r];
    int Mr = min(K + 1, MCAP);
    bool active = m < Mr;

    float px = 0.0f, py = 0.0f;
    if (m < K) { float2 pt = ((const float2*)cp)[r * MCAP + m]; px = pt.x; py = pt.y; }

    // mirror reference op order: grid = p/(S-1)*2-1 ; g = (grid+1)*(D/2)-0.5
    float gx = (px / 1295.0f * 2.0f - 1.0f + 1.0f) * 54.0f - 0.5f;
    float gy = (py / 383.0f  * 2.0f - 1.0f + 1.0f) * 16.0f - 0.5f;
    float x0 = floorf(gx), y0 = floorf(gy);
    float wx = gx - x0, wy = gy - y0;
    int x0i = (int)fminf(fmaxf(x0,         0.0f), 107.0f);
    int x1i = (int)fminf(fmaxf(x0 + 1.0f,  0.0f), 107.0f);
    int y0i = (int)fminf(fmaxf(y0,         0.0f), 31.0f);
    int y1i = (int)fminf(fmaxf(y0 + 1.0f,  0.0f), 31.0f);
    float w00 = (1.0f - wx) * (1.0f - wy);
    float w01 = wx * (1.0f - wy);
    float w10 = (1.0f - wx) * wy;
    float w11 = wx * wy;

    int c0 = g * 8;
    size_t b00 = ((size_t)(r * QPIX + y0i * QW + x0i)) * 64 + c0;
    size_t b01 = ((size_t)(r * QPIX + y0i * QW + x1i)) * 64 + c0;
    size_t b10 = ((size_t)(r * QPIX + y1i * QW + x0i)) * 64 + c0;
    size_t b11 = ((size_t)(r * QPIX + y1i * QW + x1i)) * 64 + c0;
    size_t ob  = ((size_t)(r * MCAP + m)) * 64 + c0;

    float fr[8];
    float ss = 0.0f;
    #pragma unroll
    for (int c = 0; c < 8; c += 4) {
        float4 a  = *(const float4*)(featp + b00 + c);
        float4 b_ = *(const float4*)(featp + b01 + c);
        float4 gg = *(const float4*)(featp + b10 + c);
        float4 d  = *(const float4*)(featp + b11 + c);
        float e0 = a.x * w00 + b_.x * w01 + gg.x * w10 + d.x * w11;
        float e1 = a.y * w00 + b_.y * w01 + gg.y * w10 + d.y * w11;
        float e2 = a.z * w00 + b_.z * w01 + gg.z * w10 + d.z * w11;
        float e3 = a.w * w00 + b_.w * w01 + gg.w * w10 + d.w * w11;
        fr[c] = e0; fr[c+1] = e1; fr[c+2] = e2; fr[c+3] = e3;
        ss += e0*e0; ss += e1*e1; ss += e2*e2; ss += e3*e3;
    }
    ssq[p][g] = ss;
    __syncthreads();
    float tot = 0.0f;
    #pragma unroll
    for (int i = 0; i < 8; i++) tot += ssq[p][i];
    float inv = 1.0f / fmaxf(sqrtf(tot), 1e-12f);

    if (active) {
        #pragma unroll
        for (int c = 0; c < 8; c += 4) {
            *(float4*)(cn + ob + c) =
                make_float4(fr[c]*inv, fr[c+1]*inv, fr[c+2]*inv, fr[c+3]*inv);
        }
        #pragma unroll
        for (int c = 0; c < 8; c += 4) {
            float4 a  = *(const float4*)(valp + b00 + c);
            float4 b_ = *(const float4*)(valp + b01 + c);
            float4 gg = *(const float4*)(valp + b10 + c);
            float4 d  = *(const float4*)(valp + b11 + c);
            float4 o;
            o.x = a.x * w00 + b_.x * w01 + gg.x * w10 + d.x * w11;
            o.y = a.y * w00 + b_.y * w01 + gg.y * w10 + d.y * w11;
            o.z = a.z * w00 + b_.z * w01 + gg.z * w10 + d.z * w11;
            o.w = a.w * w00 + b_.w * w01 + gg.w * w10 + d.w * w11;
            *(float4*)(vc + ob + c) = o;
        }
    }
}

// ---------------------------------------------------------------------------
// K4a v8: 128 keys x 128 centers per tile, 2 tiles/block, frag 8x8
// (1.0 B/FMA LDS traffic vs 1.5 at 4x8 -> floor 55us -> 37us). v7's proven
// staging: B staged once; A register-prefetched across tiles. All LDS reads
// broadcast or <=2-way bank aliased. LDS 64 KiB -> 2 blocks/CU.
// Grid (KT2, CSPL2, 4) x 256.
// ---------------------------------------------------------------------------
__global__ __launch_bounds__(256) void k4a_sim(
    const float* __restrict__ featp, const float* __restrict__ invn,
    const float* __restrict__ cn, const int* __restrict__ counts,
    const float* __restrict__ alpha_p, const float* __restrict__ beta_p,
    float* __restrict__ part_s, int* __restrict__ part_m)
{
    __shared__ float Bt[64 * 128];   // [ch][key]     32 KiB
    __shared__ float At[64 * 128];   // [ch][center]  32 KiB

    int r  = blockIdx.z;
    int kt = blockIdx.x;
    int sp = blockIdx.y;
    int k0 = kt * 128;
    int t  = threadIdx.x;
    int tx = t & 15, ty = t >> 4;    // tx -> 8 keys, ty -> 8 centers (2 halves each)
    int K  = counts[r];
    int Mr = min(K + 1, MCAP);
    int ntiles = (Mr + 127) >> 7;
    int ct0 = sp * 2;
    if (ct0 >= ntiles) return;       // k4b1 only reads partials for sp < ceil(nt/2)
    int ctEnd = min(ct0 + 2, ntiles);
    float alpha = alpha_p[0], beta = beta_p[0];

    int j = t >> 1, hh = (t & 1) * 32;   // staging: row j, channel-half hh

    // stage B tile: 128 keys x 64 ch, normalized, channel-major
    {
        float inv = invn[r * QPIX + k0 + j];
        const float* src = featp + ((size_t)(r * QPIX + k0 + j)) * 64 + hh;
        #pragma unroll
        for (int i = 0; i < 32; i += 4) {
            float4 fv = *(const float4*)(src + i);
            Bt[(hh + i + 0) * 128 + j] = fv.x * inv;
            Bt[(hh + i + 1) * 128 + j] = fv.y * inv;
            Bt[(hh + i + 2) * 128 + j] = fv.z * inv;
            Bt[(hh + i + 3) * 128 + j] = fv.w * inv;
        }
    }

    float best_s[8];
    int   best_m[8];
    #pragma unroll
    for (int v = 0; v < 8; v++) { best_s[v] = -INFINITY; best_m[v] = INT_MAX; }

    // preload first A tile (128 centers x 64 ch) to registers
    float4 pf[8];
    {
        int mg = min(ct0 * 128 + j, MCAP - 1);
        const float* src = cn + ((size_t)(r * MCAP + mg)) * 64 + hh;
        #pragma unroll
        for (int i = 0; i < 8; i++) pf[i] = *(const float4*)(src + i * 4);
    }
    for (int ct = ct0; ct < ctEnd; ct++) {
        __syncthreads();                    // prior At reads done
        #pragma unroll
        for (int i = 0; i < 8; i++) {
            At[(hh + i*4 + 0) * 128 + j] = pf[i].x;
            At[(hh + i*4 + 1) * 128 + j] = pf[i].y;
            At[(hh + i*4 + 2) * 128 + j] = pf[i].z;
            At[(hh + i*4 + 3) * 128 + j] = pf[i].w;
        }
        __syncthreads();                    // At (1st iter: also Bt) ready
        if (ct + 1 < ctEnd) {               // issue next-tile loads; hide under FMA
            int mg = min((ct + 1) * 128 + j, MCAP - 1);
            const float* src = cn + ((size_t)(r * MCAP + mg)) * 64 + hh;
            #pragma unroll
            for (int i = 0; i < 8; i++) pf[i] = *(const float4*)(src + i * 4);
        }

        float dot[8][8] = {};
        #pragma unroll 2
        for (int cc = 0; cc < 64; cc++) {
            float4 a0 = *(const float4*)(At + cc * 128 + ty * 4);
            float4 a1 = *(const float4*)(At + cc * 128 + 64 + ty * 4);
            float4 b0 = *(const float4*)(Bt + cc * 128 + tx * 4);
            float4 b1 = *(const float4*)(Bt + cc * 128 + 64 + tx * 4);
            float a[8] = {a0.x, a0.y, a0.z, a0.w, a1.x, a1.y, a1.z, a1.w};
            float b[8] = {b0.x, b0.y, b0.z, b0.w, b1.x, b1.y, b1.z, b1.w};
            #pragma unroll
            for (int u = 0; u < 8; u++) {
                #pragma unroll
                for (int v = 0; v < 8; v++)
                    dot[u][v] = fmaf(a[u], b[v], dot[u][v]);
            }
        }
        // running argmax; m ascending over (ct, u); strict > keeps smallest m
        // on exact fp32 ties (reference first-max rule)
        #pragma unroll
        for (int u = 0; u < 8; u++) {
            int mg = ct * 128 + ((u >> 2) << 6) + ty * 4 + (u & 3);
            bool valid = mg < Mr;
            #pragma unroll
            for (int v = 0; v < 8; v++) {
                float s = fmaf(alpha, dot[u][v], beta);  // monotone w/ sigmoid
                if (valid && s > best_s[v]) { best_s[v] = s; best_m[v] = mg; }
            }
        }
    }

    // cross-thread (ty) reduce per key; tie -> smaller m; store partials.
    // Reuse Bt as [16][128] scratch after all compute reads are done.
    __syncthreads();
    float* rs = Bt;
    int*   rm = (int*)(Bt + 2048);
    #pragma unroll
    for (int v = 0; v < 8; v++) {
        int col = ((v >> 2) << 6) + tx * 4 + (v & 3);   // key column of this best
        rs[ty * 128 + col] = best_s[v];
        rm[ty * 128 + col] = best_m[v];
    }
    __syncthreads();
    if (t < 128) {
        float bs = rs[t]; int bm = rm[t];
        #pragma unroll
        for (int y = 1; y < 16; y++) {
            float s2 = rs[y * 128 + t]; int m2 = rm[y * 128 + t];
            if (s2 > bs || (s2 == bs && m2 < bm)) { bs = s2; bm = m2; }
        }
        size_t pb = ((size_t)((r * KT2 + kt) * CSPL2 + sp)) * 128;
        part_s[pb + t] = bs;
        part_m[pb + t] = bm;
    }
}

// ---------------------------------------------------------------------------
// K4b1: reduce split partials per key (tie -> smaller m), sigmoid, and build
// the center histogram (int atomics only). Grid (KT2, 4) x 128 = 108 blocks.
// ---------------------------------------------------------------------------
__global__ __launch_bounds__(128) void k4b1_argmax(
    const float* __restrict__ part_s, const int* __restrict__ part_m,
    const int* __restrict__ counts,
    int* __restrict__ win_m, float* __restrict__ win_w, int* __restrict__ cnt)
{
    int r  = blockIdx.y;
    int kt = blockIdx.x;
    int t  = threadIdx.x;
    int gk = kt * 128 + t;
    int K  = counts[r];
    int Mr = min(K + 1, MCAP);
    int nS = (((Mr + 127) >> 7) + 1) >> 1;   // active k4a splits (2 tiles each)

    size_t pb = ((size_t)((r * KT2 + kt) * CSPL2)) * 128;
    float bs = -INFINITY; int bm = INT_MAX;
    for (int s = 0; s < nS; s++) {
        float s2 = part_s[pb + (size_t)s * 128 + t];
        int   m2 = part_m[pb + (size_t)s * 128 + t];
        if (s2 > bs || (s2 == bs && m2 < bm)) { bs = s2; bm = m2; }
    }
    if (bm < K) {   // skip phantom / empty winners
        win_m[r * QPIX + gk] = bm;
        win_w[r * QPIX + gk] = 1.0f / (1.0f + expf(-bs));
        atomicAdd(&cnt[r * MCAP + bm], 1);
    } else {
        win_m[r * QPIX + gk] = -1;
    }
}

// ---------------------------------------------------------------------------
// K4bs: exclusive scan of center histogram + ranked CSR scatter of key ids.
// Light phase only (12KB cnt + 55KB win_m reads). Grid (4) x 1024.
// ---------------------------------------------------------------------------
__global__ __launch_bounds__(1024) void k4bs_scan_scatter(
    const int* __restrict__ cnt, const int* __restrict__ win_m,
    int* __restrict__ basei, int* __restrict__ klist)
{
    __shared__ int lbase[MCAP];     // scan result, then cursor
    __shared__ int wsum[16];
    int r = blockIdx.x;
    int t = threadIdx.x;

    int i0 = t * 3;                 // 3 centers/thread (3072 = 1024*3)
    int ci = r * MCAP + i0;
    int v0 = cnt[ci], v1 = cnt[ci + 1], v2 = cnt[ci + 2];
    int s = v0 + v1 + v2;
    int lane = t & 63, w = t >> 6;
    int incl = s;
    #pragma unroll
    for (int d = 1; d < 64; d <<= 1) {
        int n = __shfl_up(incl, d, 64);
        if (lane >= d) incl += n;
    }
    if (lane == 63) wsum[w] = incl;
    __syncthreads();
    int wbase = 0;
    for (int i = 0; i < w; i++) wbase += wsum[i];
    int excl = wbase + incl - s;
    lbase[i0]     = excl;
    lbase[i0 + 1] = excl + v0;
    lbase[i0 + 2] = excl + v0 + v1;
    basei[ci]     = excl;
    basei[ci + 1] = excl + v0;
    basei[ci + 2] = excl + v0 + v1;
    __syncthreads();

    for (int gk = t; gk < QPIX; gk += 1024) {
        int bm = win_m[r * QPIX + gk];
        if (bm >= 0) {
            int pos = atomicAdd(&lbase[bm], 1);
            klist[r * QPIX + pos] = gk;
        }
    }
}

// ---------------------------------------------------------------------------
// K4c: per-center gather-sum of winner values; non-atomic agg/denom writes.
// One wave per center. Grid (MCAP/4, 4) x 256.
// ---------------------------------------------------------------------------
__global__ __launch_bounds__(256) void k4c_agg(
    const int* __restrict__ cnt, const int* __restrict__ base,
    const int* __restrict__ klist, const float* __restrict__ win_w,
    const float* __restrict__ valp,
    float* __restrict__ agg, float* __restrict__ denom)
{
    int r = blockIdx.y;
    int m = blockIdx.x * 4 + (threadIdx.x >> 6);
    int lane = threadIdx.x & 63;
    int ci = r * MCAP + m;
    int n = cnt[ci];
    if (n == 0) return;              // agg/denom stay zero (k1 zeroed)
    int b = base[ci];
    float acc = 0.0f, ds = 0.0f;
    for (int i = 0; i < n; i++) {
        int gk = klist[r * QPIX + b + i];
        float w = win_w[r * QPIX + gk];
        acc = fmaf(w, valp[((size_t)(r * QPIX + gk)) * 64 + lane], acc);
        ds += w;
    }
    agg[((size_t)ci) * 64 + lane] = acc;
    if (lane == 0) denom[ci] = ds;
}

// ---------------------------------------------------------------------------
// K5: per-point output + projection + transposed store [1,64,1,8192].
// 32 points per block; Wp row c held in 16 float4 VGPRs per thread (one-time
// L2 gather) and ov read as broadcast ds_read_b128. Same fmaf order.
// ---------------------------------------------------------------------------
__global__ __launch_bounds__(256) void k5_out(
    const float* __restrict__ agg, const float* __restrict__ vc,
    const float* __restrict__ denom, const int* __restrict__ slot,
    const float* __restrict__ Wp, const float* __restrict__ bp,
    float* __restrict__ out)
{
    __shared__ float ov[4][68];
    __shared__ float res[4][64];
    int t = threadIdx.x;
    int p = t >> 6, c = t & 63;

    float4 wr[16];
    #pragma unroll
    for (int i = 0; i < 16; i++) wr[i] = *(const float4*)(Wp + c * 64 + i * 4);
    float bc = bp[c];

    for (int pp = 0; pp < 8; pp++) {
        int n = blockIdx.x * 32 + pp * 4 + p;
        int sl = slot[n];
        float d = denom[sl] + 1.0f;
        float o_v = (agg[(size_t)sl * 64 + c] + vc[(size_t)sl * 64 + c]) / d;
        ov[p][c] = o_v;
        unsigned long long nz = __ballot(o_v != 0.0f);   // wave == point
        __syncthreads();   // ov ready
        float acc = bc;
        #pragma unroll
        for (int i = 0; i < 16; i++) {
            float4 o4 = *(const float4*)(&ov[p][i * 4]);   // broadcast b128
            acc = fmaf(o4.x, wr[i].x, acc);
            acc = fmaf(o4.y, wr[i].y, acc);
            acc = fmaf(o4.z, wr[i].z, acc);
            acc = fmaf(o4.w, wr[i].w, acc);
        }
        res[p][c] = (nz != 0ull) ? acc : 0.0f;
        __syncthreads();   // res ready; ov reads done before next-pass writes
        if (t < 64) {
            float4 val = make_float4(res[0][t], res[1][t], res[2][t], res[3][t]);
            *(float4*)(out + (size_t)t * NPTS + blockIdx.x * 32 + pp * 4) = val;
        }
    }
}

// ---------------------------------------------------------------------------
extern "C" void kernel_launch(void* const* d_in, const int* in_sizes, int n_in,
                              void* d_out, int out_size, void* d_ws, size_t ws_size,
                              hipStream_t stream) {
    const float* points = (const float*)d_in[0];
    const float* x      = (const float*)d_in[1];
    const float* Wf     = (const float*)d_in[2];
    const float* bf     = (const float*)d_in[3];
    const float* Wv     = (const float*)d_in[4];
    const float* bv     = (const float*)d_in[5];
    const float* Wp     = (const float*)d_in[6];
    const float* bp     = (const float*)d_in[7];
    const float* alpha  = (const float*)d_in[8];
    const float* beta   = (const float*)d_in[9];
    float* out = (float*)d_out;

    float* ws    = (float*)d_ws;
    float* featp = ws;                        // 884736
    float* valp  = featp + 884736;            // 884736
    float* cn    = valp  + 884736;            // 786432 (4*MCAP*64)
    float* vc    = cn    + 786432;            // 786432
    float* agg   = vc    + 786432;            // 786432  (zeroed by k1)
    float* denom = agg   + 786432;            // 12288   (zeroed by k1)
    int*   cnt   = (int*)(denom + 12288);     // 12288   (zeroed by k1)
    float* invn  = (float*)(cnt + 12288);     // 13824
    float* cp    = invn  + 13824;             // 24576 (2*4*MCAP)
    float* part_s= cp    + 24576;             // 165888 (4*27*12*128)
    int*   part_m= (int*)(part_s + 165888);   // 165888
    int*   ccnt  = part_m + 165888;           // 512
    int*   counts= ccnt   + 512;              // 16
    int*   slot  = counts + 16;               // 8192
    int*   win_m = slot   + 8192;             // 13824
    float* win_w = (float*)(win_m + 13824);   // 13824
    int*   basei = (int*)(win_w + 13824);     // 12288
    int*   klist = basei  + 12288;            // 13824
    // total ~16 MB of d_ws

    k1_linmaps<<<232, 512, 0, stream>>>(x, Wf, bf, Wv, bv, featp, valp, invn, agg,
                                        points, ccnt);
    k2c_scatter<<<128, 64, 0, stream>>>(points, ccnt, cp, slot, counts);
    k3_gather<<<dim3(MCAP / 32, 4), 256, 0, stream>>>(featp, valp, cp, counts, cn, vc);
    k4a_sim<<<dim3(KT2, CSPL2, 4), 256, 0, stream>>>(featp, invn, cn, counts,
                                                     alpha, beta, part_s, part_m);
    k4b1_argmax<<<dim3(KT2, 4), 128, 0, stream>>>(part_s, part_m, counts,
                                                  win_m, win_w, cnt);
    k4bs_scan_scatter<<<4, 1024, 0, stream>>>(cnt, win_m, basei, klist);
    k4c_agg<<<dim3(MCAP / 4, 4), 256, 0, stream>>>(cnt, basei, klist, win_w,
                                                   valp, agg, denom);
    k5_out<<<NPTS / 32, 256, 0, stream>>>(agg, vc, denom, slot, Wp, bp, out);
}

// Round 11
// 193.347 us; speedup vs baseline: 1.0249x; 1.0249x over previous
//
#include <hip/hip_runtime.h>
#include <math.h>
#include <float.h>
#include <limits.h>

// Problem constants
#define PIX    13824   // 64*216
#define QPIX   3456    // 32*108
#define QW     108
#define QH     32
#define NPTS   8192
#define MCAP   3072    // per-quadrant center capacity (expected ~2048, 26 sigma)
#define KT2    27      // QPIX/128 (k4a key tiles)
#define CSPL   24      // center-splits: each block 2 x 64-center tiles

// ---------------------------------------------------------------------------
// K1: feat/value linear maps + fold to [r][k][c] pixel-major + feat inv-norm.
// Blocks 0..215: linmaps (8 waves x 8 outputs). Blocks 216..231: per-chunk
// quadrant counts (folded k2a). Also zeroes agg+denom+cnt.
// ---------------------------------------------------------------------------
__device__ __forceinline__ int point_quadrant(float px, float py) {
    // rh = 384/2 = 192 exact, rw = 1296/2 = 648 exact
    return ((py > 192.0f) ? 2 : 0) + ((px > 648.0f) ? 1 : 0);
}

__global__ __launch_bounds__(512) void k1_linmaps(
    const float* __restrict__ x, const float* __restrict__ Wf, const float* __restrict__ bf,
    const float* __restrict__ Wv, const float* __restrict__ bv,
    float* __restrict__ featp, float* __restrict__ valp, float* __restrict__ invn,
    float* __restrict__ aggz,
    const float* __restrict__ points, int* __restrict__ ccnt)
{
    __shared__ float ssq[8][64];
    int t = threadIdx.x;

    // zero agg(786432) + denom(12288) + cnt(12288) = 811008 floats = 202752 float4
    {
        float4 z4 = make_float4(0.f, 0.f, 0.f, 0.f);
        for (int i = blockIdx.x * 512 + t; i < 202752; i += 232 * 512)
            ((float4*)aggz)[i] = z4;
    }

    int lane = t & 63;
    int q = t >> 6;                       // wave id (wave-uniform)

    if (blockIdx.x >= 216) {              // k2a work: wave == 64-point chunk
        int chunk = (blockIdx.x - 216) * 8 + q;
        float2 p = ((const float2*)points)[chunk * 64 + lane];
        int qd = point_quadrant(p.x, p.y);
        #pragma unroll
        for (int r = 0; r < 4; r++) {
            unsigned long long m = __ballot(qd == r);
            if (lane == 0) ccnt[chunk * 4 + r] = __popcll(m);
        }
        return;
    }

    int pix = blockIdx.x * 64 + lane;     // 216*64 = 13824 exact
    int h = pix / 216;
    int w = pix - h * 216;
    int r = ((h >> 5) << 1) | (w >= QW ? 1 : 0);
    int k = (h & 31) * QW + (w >= QW ? w - QW : w);

    float xr[64];
    #pragma unroll
    for (int c = 0; c < 64; c++) xr[c] = x[c * PIX + pix];

    size_t base = ((size_t)(r * QPIX + k)) * 64 + q * 8;
    float ss = 0.0f;
    for (int i = 0; i < 8; i++) {
        int o = q * 8 + i;                // wave-uniform
        float af = bf[o], av = bv[o];
        #pragma unroll
        for (int c = 0; c < 64; c++) {
            af = fmaf(Wf[o * 64 + c], xr[c], af);
            av = fmaf(Wv[o * 64 + c], xr[c], av);
        }
        featp[base + i] = af;
        valp[base + i]  = av;
        ss += af * af;
    }
    ssq[q][lane] = ss;
    __syncthreads();
    if (q == 0) {
        float tot = 0.0f;
        #pragma unroll
        for (int i = 0; i < 8; i++) tot += ssq[i][lane];
        invn[r * QPIX + k] = 1.0f / fmaxf(sqrtf(tot), 1e-12f);
    }
}

// ---------------------------------------------------------------------------
// K2c: per-block redundant scan of chunk counts + ranked order-preserving
// scatter of points into per-quadrant compacted arrays.
// ---------------------------------------------------------------------------
__global__ __launch_bounds__(64) void k2c_scatter(
    const float* __restrict__ points, const int* __restrict__ ccnt,
    float* __restrict__ cp, int* __restrict__ slot, int* __restrict__ counts)
{
    int lane = threadIdx.x;
    int chunk = blockIdx.x;

    // redundant per-block scan: prefix over chunks < my chunk, per quadrant
    int c0[4], c1[4], pre[4];
    #pragma unroll
    for (int r = 0; r < 4; r++) {
        c0[r] = ccnt[lane * 4 + r];
        c1[r] = ccnt[(lane + 64) * 4 + r];
        pre[r] = (lane < chunk ? c0[r] : 0) + (lane + 64 < chunk ? c1[r] : 0);
    }
    #pragma unroll
    for (int d = 1; d < 64; d <<= 1) {
        #pragma unroll
        for (int r = 0; r < 4; r++) pre[r] += __shfl_xor(pre[r], d, 64);
    }
    if (chunk == 0) {   // block 0 also publishes the totals
        int full[4];
        #pragma unroll
        for (int r = 0; r < 4; r++) full[r] = c0[r] + c1[r];
        #pragma unroll
        for (int d = 1; d < 64; d <<= 1) {
            #pragma unroll
            for (int r = 0; r < 4; r++) full[r] += __shfl_xor(full[r], d, 64);
        }
        if (lane == 0) {
            #pragma unroll
            for (int r = 0; r < 4; r++) counts[r] = full[r];
        }
    }

    int n = chunk * 64 + lane;
    float2 p = ((const float2*)points)[n];
    int q = point_quadrant(p.x, p.y);
    unsigned long long below = (lane == 0) ? 0ull : (~0ull >> (64 - lane));
    #pragma unroll
    for (int r = 0; r < 4; r++) {
        unsigned long long m = __ballot(q == r);
        if (q == r) {
            int pos = pre[r] + __popcll(m & below);
            ((float2*)cp)[r * MCAP + pos] = p;
            slot[n] = r * MCAP + pos;
        }
    }
}

// ---------------------------------------------------------------------------
// K3: bilinear gather (border clamp) of feat & value at compacted points;
// slot m == K_r is the phantom (0,0) padded row. 8 channel-groups x 32 points
// per block (256 threads, 8 ch/thread).
// ---------------------------------------------------------------------------
__global__ __launch_bounds__(256) void k3_gather(
    const float* __restrict__ featp, const float* __restrict__ valp,
    const float* __restrict__ cp, const int* __restrict__ counts,
    float* __restrict__ cn, float* __restrict__ vc)
{
    __shared__ float ssq[32][9];
    int r = blockIdx.y;
    int t = threadIdx.x;
    int g = t & 7, p = t >> 3;          // g: channel group (8ch), p: point in tile
    int m = blockIdx.x * 32 + p;
    int K = counts[r];
    int Mr = min(K + 1, MCAP);
    bool active = m < Mr;

    float px = 0.0f, py = 0.0f;
    if (m < K) { float2 pt = ((const float2*)cp)[r * MCAP + m]; px = pt.x; py = pt.y; }

    // mirror reference op order: grid = p/(S-1)*2-1 ; g = (grid+1)*(D/2)-0.5
    float gx = (px / 1295.0f * 2.0f - 1.0f + 1.0f) * 54.0f - 0.5f;
    float gy = (py / 383.0f  * 2.0f - 1.0f + 1.0f) * 16.0f - 0.5f;
    float x0 = floorf(gx), y0 = floorf(gy);
    float wx = gx - x0, wy = gy - y0;
    int x0i = (int)fminf(fmaxf(x0,         0.0f), 107.0f);
    int x1i = (int)fminf(fmaxf(x0 + 1.0f,  0.0f), 107.0f);
    int y0i = (int)fminf(fmaxf(y0,         0.0f), 31.0f);
    int y1i = (int)fminf(fmaxf(y0 + 1.0f,  0.0f), 31.0f);
    float w00 = (1.0f - wx) * (1.0f - wy);
    float w01 = wx * (1.0f - wy);
    float w10 = (1.0f - wx) * wy;
    float w11 = wx * wy;

    int c0 = g * 8;
    size_t b00 = ((size_t)(r * QPIX + y0i * QW + x0i)) * 64 + c0;
    size_t b01 = ((size_t)(r * QPIX + y0i * QW + x1i)) * 64 + c0;
    size_t b10 = ((size_t)(r * QPIX + y1i * QW + x0i)) * 64 + c0;
    size_t b11 = ((size_t)(r * QPIX + y1i * QW + x1i)) * 64 + c0;
    size_t ob  = ((size_t)(r * MCAP + m)) * 64 + c0;

    float fr[8];
    float ss = 0.0f;
    #pragma unroll
    for (int c = 0; c < 8; c += 4) {
        float4 a  = *(const float4*)(featp + b00 + c);
        float4 b_ = *(const float4*)(featp + b01 + c);
        float4 gg = *(const float4*)(featp + b10 + c);
        float4 d  = *(const float4*)(featp + b11 + c);
        float e0 = a.x * w00 + b_.x * w01 + gg.x * w10 + d.x * w11;
        float e1 = a.y * w00 + b_.y * w01 + gg.y * w10 + d.y * w11;
        float e2 = a.z * w00 + b_.z * w01 + gg.z * w10 + d.z * w11;
        float e3 = a.w * w00 + b_.w * w01 + gg.w * w10 + d.w * w11;
        fr[c] = e0; fr[c+1] = e1; fr[c+2] = e2; fr[c+3] = e3;
        ss += e0*e0; ss += e1*e1; ss += e2*e2; ss += e3*e3;
    }
    ssq[p][g] = ss;
    __syncthreads();
    float tot = 0.0f;
    #pragma unroll
    for (int i = 0; i < 8; i++) tot += ssq[p][i];
    float inv = 1.0f / fmaxf(sqrtf(tot), 1e-12f);

    if (active) {
        #pragma unroll
        for (int c = 0; c < 8; c += 4) {
            *(float4*)(cn + ob + c) =
                make_float4(fr[c]*inv, fr[c+1]*inv, fr[c+2]*inv, fr[c+3]*inv);
        }
        #pragma unroll
        for (int c = 0; c < 8; c += 4) {
            float4 a  = *(const float4*)(valp + b00 + c);
            float4 b_ = *(const float4*)(valp + b01 + c);
            float4 gg = *(const float4*)(valp + b10 + c);
            float4 d  = *(const float4*)(valp + b11 + c);
            float4 o;
            o.x = a.x * w00 + b_.x * w01 + gg.x * w10 + d.x * w11;
            o.y = a.y * w00 + b_.y * w01 + gg.y * w10 + d.y * w11;
            o.z = a.z * w00 + b_.z * w01 + gg.z * w10 + d.z * w11;
            o.w = a.w * w00 + b_.w * w01 + gg.w * w10 + d.w * w11;
            *(float4*)(vc + ob + c) = o;
        }
    }
}

// ---------------------------------------------------------------------------
// K4a v7 (final): 128 keys x 64 centers/tile, 2 tiles/block, frag 4x8,
// LDS 48 KiB -> 3 blocks/CU, register-prefetched A staging. Measured at ~91%
// of its ds_read_b128 throughput floor. 8x8 frags refuted 3x (v1/v6/v8):
// occupancy/latency term dominates the LDS-per-FMA ratio on this problem.
// ---------------------------------------------------------------------------
__global__ __launch_bounds__(256) void k4a_sim(
    const float* __restrict__ featp, const float* __restrict__ invn,
    const float* __restrict__ cn, const int* __restrict__ counts,
    const float* __restrict__ alpha_p, const float* __restrict__ beta_p,
    float* __restrict__ part_s, int* __restrict__ part_m)
{
    __shared__ float Bt[64 * 128];   // [ch][key]     32 KiB
    __shared__ float At[64 * 64];    // [ch][center]  16 KiB

    int r  = blockIdx.z;
    int kt = blockIdx.x;
    int sp = blockIdx.y;
    int k0 = kt * 128;
    int t  = threadIdx.x;
    int tx = t & 15, ty = t >> 4;    // tx -> 8 keys (2 groups of 4), ty -> 4 centers
    int K  = counts[r];
    int Mr = min(K + 1, MCAP);
    int ntiles = (Mr + 63) >> 6;
    int ct0 = sp * 2;
    if (ct0 >= ntiles) return;       // k4b1 only reads partials for sp < ceil(nt/2)
    int ctEnd = min(ct0 + 2, ntiles);
    float alpha = alpha_p[0], beta = beta_p[0];

    // stage B tile: 128 keys x 64 ch, normalized, channel-major
    {
        int j = t >> 1, hh = (t & 1) * 32;
        float inv = invn[r * QPIX + k0 + j];
        const float* src = featp + ((size_t)(r * QPIX + k0 + j)) * 64 + hh;
        #pragma unroll
        for (int i = 0; i < 32; i += 4) {
            float4 fv = *(const float4*)(src + i);
            Bt[(hh + i + 0) * 128 + j] = fv.x * inv;
            Bt[(hh + i + 1) * 128 + j] = fv.y * inv;
            Bt[(hh + i + 2) * 128 + j] = fv.z * inv;
            Bt[(hh + i + 3) * 128 + j] = fv.w * inv;
        }
    }

    float best_s[8];
    int   best_m[8];
    #pragma unroll
    for (int v = 0; v < 8; v++) { best_s[v] = -INFINITY; best_m[v] = INT_MAX; }

    int aj = t & 63, ack = (t >> 6) * 16;   // A-staging: center row / ch-chunk
    // preload first A sub-tile to registers
    float4 pf[4];
    {
        int mg = min(ct0 * 64 + aj, MCAP - 1);
        const float* src = cn + ((size_t)(r * MCAP + mg)) * 64 + ack;
        #pragma unroll
        for (int i = 0; i < 4; i++) pf[i] = *(const float4*)(src + i * 4);
    }
    for (int ct = ct0; ct < ctEnd; ct++) {
        __syncthreads();                    // prior At reads done (1st: covers Bt)
        #pragma unroll
        for (int i = 0; i < 4; i++) {
            At[(ack + i * 4 + 0) * 64 + aj] = pf[i].x;
            At[(ack + i * 4 + 1) * 64 + aj] = pf[i].y;
            At[(ack + i * 4 + 2) * 64 + aj] = pf[i].z;
            At[(ack + i * 4 + 3) * 64 + aj] = pf[i].w;
        }
        __syncthreads();
        if (ct + 1 < ctEnd) {               // issue next-tile loads; hide under FMA
            int mg = min((ct + 1) * 64 + aj, MCAP - 1);
            const float* src = cn + ((size_t)(r * MCAP + mg)) * 64 + ack;
            #pragma unroll
            for (int i = 0; i < 4; i++) pf[i] = *(const float4*)(src + i * 4);
        }

        float dot[4][8] = {};
        #pragma unroll 4
        for (int cc = 0; cc < 64; cc++) {
            float4 a0 = *(const float4*)(At + cc * 64 + ty * 4);
            float4 b0 = *(const float4*)(Bt + cc * 128 + tx * 4);
            float4 b1 = *(const float4*)(Bt + cc * 128 + 64 + tx * 4);
            float a[4] = {a0.x, a0.y, a0.z, a0.w};
            float b[8] = {b0.x, b0.y, b0.z, b0.w, b1.x, b1.y, b1.z, b1.w};
            #pragma unroll
            for (int u = 0; u < 4; u++) {
                #pragma unroll
                for (int v = 0; v < 8; v++)
                    dot[u][v] = fmaf(a[u], b[v], dot[u][v]);
            }
        }
        // running argmax; m ascending (ct, then u); strict > keeps smallest m
        // on exact fp32 ties (reference first-max rule)
        #pragma unroll
        for (int u = 0; u < 4; u++) {
            int mg = ct * 64 + ty * 4 + u;
            bool valid = mg < Mr;
            #pragma unroll
            for (int v = 0; v < 8; v++) {
                float s = fmaf(alpha, dot[u][v], beta);  // monotone w/ sigmoid
                if (valid && s > best_s[v]) { best_s[v] = s; best_m[v] = mg; }
            }
        }
    }

    // cross-thread (ty) reduce per key; tie -> smaller m; store partials.
    // Reuse Bt as [16][128] scratch after all compute reads are done.
    __syncthreads();
    float* rs = Bt;
    int*   rm = (int*)(Bt + 2048);
    #pragma unroll
    for (int v = 0; v < 8; v++) {
        int col = tx * 4 + (v & 3) + ((v >> 2) << 6);   // key column of this best
        rs[ty * 128 + col] = best_s[v];
        rm[ty * 128 + col] = best_m[v];
    }
    __syncthreads();
    if (t < 128) {
        float bs = rs[t]; int bm = rm[t];
        #pragma unroll
        for (int y = 1; y < 16; y++) {
            float s2 = rs[y * 128 + t]; int m2 = rm[y * 128 + t];
            if (s2 > bs || (s2 == bs && m2 < bm)) { bs = s2; bm = m2; }
        }
        size_t pb = ((size_t)((r * KT2 + kt) * CSPL + sp)) * 128;
        part_s[pb + t] = bs;
        part_m[pb + t] = bm;
    }
}

// ---------------------------------------------------------------------------
// K4b1: reduce split partials per key (tie -> smaller m), sigmoid, and build
// the center histogram (int atomics only). Grid (KT2, 4) x 128 = 108 blocks.
// ---------------------------------------------------------------------------
__global__ __launch_bounds__(128) void k4b1_argmax(
    const float* __restrict__ part_s, const int* __restrict__ part_m,
    const int* __restrict__ counts,
    int* __restrict__ win_m, float* __restrict__ win_w, int* __restrict__ cnt)
{
    int r  = blockIdx.y;
    int kt = blockIdx.x;
    int t  = threadIdx.x;
    int gk = kt * 128 + t;
    int K  = counts[r];
    int Mr = min(K + 1, MCAP);
    int nS = (((Mr + 63) >> 6) + 1) >> 1;   // active k4a splits (2 tiles each)

    size_t pb = ((size_t)((r * KT2 + kt) * CSPL)) * 128;
    float bs = -INFINITY; int bm = INT_MAX;
    for (int s = 0; s < nS; s++) {
        float s2 = part_s[pb + (size_t)s * 128 + t];
        int   m2 = part_m[pb + (size_t)s * 128 + t];
        if (s2 > bs || (s2 == bs && m2 < bm)) { bs = s2; bm = m2; }
    }
    if (bm < K) {   // skip phantom / empty winners
        win_m[r * QPIX + gk] = bm;
        win_w[r * QPIX + gk] = 1.0f / (1.0f + expf(-bs));
        atomicAdd(&cnt[r * MCAP + bm], 1);
    } else {
        win_m[r * QPIX + gk] = -1;
    }
}

// ---------------------------------------------------------------------------
// K4bs: exclusive scan of center histogram + ranked CSR scatter of key ids.
// Light phase only (12KB cnt + 55KB win_m reads). Grid (4) x 1024.
// ---------------------------------------------------------------------------
__global__ __launch_bounds__(1024) void k4bs_scan_scatter(
    const int* __restrict__ cnt, const int* __restrict__ win_m,
    int* __restrict__ basei, int* __restrict__ klist)
{
    __shared__ int lbase[MCAP];     // scan result, then cursor
    __shared__ int wsum[16];
    int r = blockIdx.x;
    int t = threadIdx.x;

    int i0 = t * 3;                 // 3 centers/thread (3072 = 1024*3)
    int ci = r * MCAP + i0;
    int v0 = cnt[ci], v1 = cnt[ci + 1], v2 = cnt[ci + 2];
    int s = v0 + v1 + v2;
    int lane = t & 63, w = t >> 6;
    int incl = s;
    #pragma unroll
    for (int d = 1; d < 64; d <<= 1) {
        int n = __shfl_up(incl, d, 64);
        if (lane >= d) incl += n;
    }
    if (lane == 63) wsum[w] = incl;
    __syncthreads();
    int wbase = 0;
    for (int i = 0; i < w; i++) wbase += wsum[i];
    int excl = wbase + incl - s;
    lbase[i0]     = excl;
    lbase[i0 + 1] = excl + v0;
    lbase[i0 + 2] = excl + v0 + v1;
    basei[ci]     = excl;
    basei[ci + 1] = excl + v0;
    basei[ci + 2] = excl + v0 + v1;
    __syncthreads();

    for (int gk = t; gk < QPIX; gk += 1024) {
        int bm = win_m[r * QPIX + gk];
        if (bm >= 0) {
            int pos = atomicAdd(&lbase[bm], 1);
            klist[r * QPIX + pos] = gk;
        }
    }
}

// ---------------------------------------------------------------------------
// K4c: per-center gather-sum of winner values; non-atomic agg/denom writes.
// One wave per center. Grid (MCAP/4, 4) x 256.
// ---------------------------------------------------------------------------
__global__ __launch_bounds__(256) void k4c_agg(
    const int* __restrict__ cnt, const int* __restrict__ base,
    const int* __restrict__ klist, const float* __restrict__ win_w,
    const float* __restrict__ valp,
    float* __restrict__ agg, float* __restrict__ denom)
{
    int r = blockIdx.y;
    int m = blockIdx.x * 4 + (threadIdx.x >> 6);
    int lane = threadIdx.x & 63;
    int ci = r * MCAP + m;
    int n = cnt[ci];
    if (n == 0) return;              // agg/denom stay zero (k1 zeroed)
    int b = base[ci];
    float acc = 0.0f, ds = 0.0f;
    for (int i = 0; i < n; i++) {
        int gk = klist[r * QPIX + b + i];
        float w = win_w[r * QPIX + gk];
        acc = fmaf(w, valp[((size_t)(r * QPIX + gk)) * 64 + lane], acc);
        ds += w;
    }
    agg[((size_t)ci) * 64 + lane] = acc;
    if (lane == 0) denom[ci] = ds;
}

// ---------------------------------------------------------------------------
// K5: per-point output + projection + transposed store [1,64,1,8192].
// 32 points per block; Wp row c held in 16 float4 VGPRs per thread (one-time
// L2 gather) and ov read as broadcast ds_read_b128. Same fmaf order.
// ---------------------------------------------------------------------------
__global__ __launch_bounds__(256) void k5_out(
    const float* __restrict__ agg, const float* __restrict__ vc,
    const float* __restrict__ denom, const int* __restrict__ slot,
    const float* __restrict__ Wp, const float* __restrict__ bp,
    float* __restrict__ out)
{
    __shared__ float ov[4][68];
    __shared__ float res[4][64];
    int t = threadIdx.x;
    int p = t >> 6, c = t & 63;

    float4 wr[16];
    #pragma unroll
    for (int i = 0; i < 16; i++) wr[i] = *(const float4*)(Wp + c * 64 + i * 4);
    float bc = bp[c];

    for (int pp = 0; pp < 8; pp++) {
        int n = blockIdx.x * 32 + pp * 4 + p;
        int sl = slot[n];
        float d = denom[sl] + 1.0f;
        float o_v = (agg[(size_t)sl * 64 + c] + vc[(size_t)sl * 64 + c]) / d;
        ov[p][c] = o_v;
        unsigned long long nz = __ballot(o_v != 0.0f);   // wave == point
        __syncthreads();   // ov ready
        float acc = bc;
        #pragma unroll
        for (int i = 0; i < 16; i++) {
            float4 o4 = *(const float4*)(&ov[p][i * 4]);   // broadcast b128
            acc = fmaf(o4.x, wr[i].x, acc);
            acc = fmaf(o4.y, wr[i].y, acc);
            acc = fmaf(o4.z, wr[i].z, acc);
            acc = fmaf(o4.w, wr[i].w, acc);
        }
        res[p][c] = (nz != 0ull) ? acc : 0.0f;
        __syncthreads();   // res ready; ov reads done before next-pass writes
        if (t < 64) {
            float4 val = make_float4(res[0][t], res[1][t], res[2][t], res[3][t]);
            *(float4*)(out + (size_t)t * NPTS + blockIdx.x * 32 + pp * 4) = val;
        }
    }
}

// ---------------------------------------------------------------------------
extern "C" void kernel_launch(void* const* d_in, const int* in_sizes, int n_in,
                              void* d_out, int out_size, void* d_ws, size_t ws_size,
                              hipStream_t stream) {
    const float* points = (const float*)d_in[0];
    const float* x      = (const float*)d_in[1];
    const float* Wf     = (const float*)d_in[2];
    const float* bf     = (const float*)d_in[3];
    const float* Wv     = (const float*)d_in[4];
    const float* bv     = (const float*)d_in[5];
    const float* Wp     = (const float*)d_in[6];
    const float* bp     = (const float*)d_in[7];
    const float* alpha  = (const float*)d_in[8];
    const float* beta   = (const float*)d_in[9];
    float* out = (float*)d_out;

    float* ws    = (float*)d_ws;
    float* featp = ws;                        // 884736
    float* valp  = featp + 884736;            // 884736
    float* cn    = valp  + 884736;            // 786432 (4*MCAP*64)
    float* vc    = cn    + 786432;            // 786432
    float* agg   = vc    + 786432;            // 786432  (zeroed by k1)
    float* denom = agg   + 786432;            // 12288   (zeroed by k1)
    int*   cnt   = (int*)(denom + 12288);     // 12288   (zeroed by k1)
    float* invn  = (float*)(cnt + 12288);     // 13824
    float* cp    = invn  + 13824;             // 24576 (2*4*MCAP)
    float* part_s= cp    + 24576;             // 331776 (4*27*24*128)
    int*   part_m= (int*)(part_s + 331776);   // 331776
    int*   ccnt  = part_m + 331776;           // 512
    int*   counts= ccnt   + 512;              // 16
    int*   slot  = counts + 16;               // 8192
    int*   win_m = slot   + 8192;             // 13824
    float* win_w = (float*)(win_m + 13824);   // 13824
    int*   basei = (int*)(win_w + 13824);     // 12288
    int*   klist = basei  + 12288;            // 13824
    // total ~17 MB of d_ws

    k1_linmaps<<<232, 512, 0, stream>>>(x, Wf, bf, Wv, bv, featp, valp, invn, agg,
                                        points, ccnt);
    k2c_scatter<<<128, 64, 0, stream>>>(points, ccnt, cp, slot, counts);
    k3_gather<<<dim3(MCAP / 32, 4), 256, 0, stream>>>(featp, valp, cp, counts, cn, vc);
    k4a_sim<<<dim3(KT2, CSPL, 4), 256, 0, stream>>>(featp, invn, cn, counts,
                                                    alpha, beta, part_s, part_m);
    k4b1_argmax<<<dim3(KT2, 4), 128, 0, stream>>>(part_s, part_m, counts,
                                                  win_m, win_w, cnt);
    k4bs_scan_scatter<<<4, 1024, 0, stream>>>(cnt, win_m, basei, klist);
    k4c_agg<<<dim3(MCAP / 4, 4), 256, 0, stream>>>(cnt, basei, klist, win_w,
                                                   valp, agg, denom);
    k5_out<<<NPTS / 32, 256, 0, stream>>>(agg, vc, denom, slot, Wp, bp, out);
}